// Round 14
// baseline (1242.099 us; speedup 1.0000x reference)
//
#include <hip/hip_runtime.h>
#include <hip/hip_fp16.h>

#define N_GRAPHS 32
#define NUM_NODES 2848
#define NTOT (N_GRAPHS * NUM_NODES)   // 91136
#define NE 1000000
#define KS 3
#define TL 5
#define HID 32
#define EPSV 1e-5f
#define SCAN_B 256
#define NBLK (NTOT / SCAN_B)          // 356 (exact)
#define NBINS 64
#define CNTN (NBINS * NBLK)           // 22784
#define CNTB (CNTN / SCAN_B)          // 89
#define NT8 (NTOT * 8)                // uints per section ([NTOT][8] uints = 2.9MB)
#define NB128 (NTOT / 128)            // 712
#define SRCMASK 0x1FFFFu

typedef unsigned uintx4 __attribute__((ext_vector_type(4)));

// ---------------- bf16 / fp15 helpers ----------------

__device__ __forceinline__ float2 unpk(unsigned u) {
    return make_float2(__uint_as_float(u << 16), __uint_as_float(u & 0xffff0000u));
}
__device__ __forceinline__ unsigned bf16rn(float f) {
    unsigned x = __float_as_uint(f);
    return (x + 0x7fffu + ((x >> 16) & 1u)) >> 16;
}
__device__ __forceinline__ unsigned pk(float a, float b) {
    return bf16rn(a) | (bf16rn(b) << 16);
}
__device__ __forceinline__ float dec_nm(unsigned q) {
    return __half2float(__ushort_as_half((unsigned short)(q >> 17)));
}

// ---------------- graph preprocessing ----------------

__global__ void k_cnt(const int* __restrict__ col, int* __restrict__ indegS) {
    int e = blockIdx.x * blockDim.x + threadIdx.x;
    if (e < NE) atomicAdd(&indegS[(col[e] << 2) | (e & 3)], 1);
}

__global__ void k_merge(const int* __restrict__ indegS, int* __restrict__ indeg) {
    int n = blockIdx.x * blockDim.x + threadIdx.x;
    if (n < NTOT) {
        int4 v = ((const int4*)indegS)[n];
        indeg[n] = v.x + v.y + v.z + v.w;
    }
}

__global__ void k_lhist(const int* __restrict__ indeg, int* __restrict__ cnt) {
    __shared__ int h[NBINS];
    int t = threadIdx.x;
    if (t < NBINS) h[t] = 0;
    __syncthreads();
    int n = blockIdx.x * SCAN_B + t;
    atomicAdd(&h[min(indeg[n], NBINS - 1)], 1);
    __syncthreads();
    if (t < NBINS) cnt[t * NBLK + blockIdx.x] = h[t];
}

__global__ void k_scan1(const int* __restrict__ in, int* __restrict__ bsum) {
    __shared__ int s[SCAN_B];
    int i = blockIdx.x * SCAN_B + threadIdx.x;
    s[threadIdx.x] = in[i];
    __syncthreads();
    for (int st = SCAN_B / 2; st >= 1; st >>= 1) {
        if (threadIdx.x < st) s[threadIdx.x] += s[threadIdx.x + st];
        __syncthreads();
    }
    if (threadIdx.x == 0) bsum[blockIdx.x] = s[0];
}

__global__ void k_scan2(int* __restrict__ bsum, int n) {
    __shared__ int s[512];
    int t = threadIdx.x;
    int v = (t < n) ? bsum[t] : 0;
    s[t] = v;
    __syncthreads();
    for (int off = 1; off < 512; off <<= 1) {
        int a = (t >= off) ? s[t - off] : 0;
        __syncthreads();
        s[t] += a;
        __syncthreads();
    }
    if (t < n) bsum[t] = s[t] - v;   // exclusive
}

__global__ void k_scan3(const int* __restrict__ in, const int* __restrict__ bsum,
                        int* __restrict__ out, int sentIdx, int sentVal) {
    __shared__ int s[SCAN_B];
    int i = blockIdx.x * SCAN_B + threadIdx.x;
    int v = in[i];
    s[threadIdx.x] = v;
    __syncthreads();
    for (int off = 1; off < SCAN_B; off <<= 1) {
        int a = (threadIdx.x >= off) ? s[threadIdx.x - off] : 0;
        __syncthreads();
        s[threadIdx.x] += a;
        __syncthreads();
    }
    out[i] = bsum[blockIdx.x] + s[threadIdx.x] - v;
    if (i == 0 && sentIdx >= 0) out[sentIdx] = sentVal;
}

__global__ void k_rank(const int* __restrict__ indeg, const int* __restrict__ cnt,
                       int* __restrict__ perm, int* __restrict__ invperm,
                       int* __restrict__ indegp) {
    __shared__ int base[NBINS];
    __shared__ int cur[NBINS];
    int t = threadIdx.x;
    if (t < NBINS) { base[t] = cnt[t * NBLK + blockIdx.x]; cur[t] = 0; }
    __syncthreads();
    int n = blockIdx.x * SCAN_B + t;
    int dg = indeg[n];
    int b = min(dg, NBINS - 1);
    int pos = base[b] + atomicAdd(&cur[b], 1);
    perm[pos] = n;
    invperm[n] = pos;
    indegp[pos] = dg;
}

__global__ void k_xp(const float2* __restrict__ x, const int* __restrict__ perm,
                     float2* __restrict__ xp) {
    int i = blockIdx.x * blockDim.x + threadIdx.x;
    if (i < NTOT) xp[i] = x[perm[i]];
}

__global__ void k_fill(const int* __restrict__ row, const int* __restrict__ col,
                       const float* __restrict__ w, const int* __restrict__ invperm,
                       int* __restrict__ cursor, unsigned* __restrict__ adjc) {
    int e = blockIdx.x * blockDim.x + threadIdx.x;
    if (e < NE) {
        int pr = invperm[row[e]], pc = invperm[col[e]];
        int p = atomicAdd(&cursor[pc], 1);
        unsigned short hb = __half_as_ushort(__float2half(w[e]));   // sign bit = 0
        adjc[p] = ((unsigned)hb << 17) | (unsigned)pr;
    }
}

__global__ void k_degdis(const unsigned* __restrict__ adjc, const int* __restrict__ offs,
                         float* __restrict__ disp) {
    int n = blockIdx.x * blockDim.x + threadIdx.x;
    if (n >= NTOT) return;
    int e0 = offs[n], e1 = offs[n + 1];
    float d = 0.f;
    for (int e = e0; e < e1; ++e) d += dec_nm(adjc[e]);
    disp[n] = (d > 0.f) ? rsqrtf(d) : 0.f;
}

__global__ void k_norm(unsigned* __restrict__ adjc, const int* __restrict__ offs,
                       const float* __restrict__ disp) {
    int n = blockIdx.x * blockDim.x + threadIdx.x;
    if (n >= NTOT) return;
    float dc = disp[n];
    int e0 = offs[n], e1 = offs[n + 1];
    for (int e = e0; e < e1; ++e) {
        unsigned q = adjc[e];
        float nm = dc * dec_nm(q) * disp[q & SRCMASK];
        unsigned short hb = __half_as_ushort(__float2half(nm));
        adjc[e] = ((unsigned)hb << 17) | (q & SRCMASK);
    }
}

// ---------------- sectioned gather (R9 version, proven 68us) ----------------

__global__ __launch_bounds__(256) void k_gath(
    const unsigned* __restrict__ SRC, const int* __restrict__ offs,
    const unsigned* __restrict__ adjc, unsigned* __restrict__ P) {
    int tid = threadIdx.x;
    int u = tid & 1;
    int nl = tid >> 1;               // 0..127
    int bid = blockIdx.x;
    int s = bid / NB128;
    int node = (bid - s * NB128) * 128 + nl;
    const uintx4* src = (const uintx4*)(SRC + (size_t)s * NT8);
    float a0 = 0.f, a1 = 0.f, a2 = 0.f, a3 = 0.f, a4 = 0.f, a5 = 0.f, a6 = 0.f, a7 = 0.f;
    int e0 = offs[node], e1 = offs[node + 1];
    int e = e0;
    for (; e + 4 <= e1; e += 4) {
        unsigned q0 = __builtin_nontemporal_load(adjc + e);
        unsigned q1 = __builtin_nontemporal_load(adjc + e + 1);
        unsigned q2 = __builtin_nontemporal_load(adjc + e + 2);
        unsigned q3 = __builtin_nontemporal_load(adjc + e + 3);
        uintx4 v0 = src[(q0 & SRCMASK) * 2 + u];
        uintx4 v1 = src[(q1 & SRCMASK) * 2 + u];
        uintx4 v2 = src[(q2 & SRCMASK) * 2 + u];
        uintx4 v3 = src[(q3 & SRCMASK) * 2 + u];
        float n0 = dec_nm(q0), n1 = dec_nm(q1), n2 = dec_nm(q2), n3 = dec_nm(q3);
        float2 t;
        t = unpk(v0.x); a0 += n0 * t.x; a1 += n0 * t.y;
        t = unpk(v0.y); a2 += n0 * t.x; a3 += n0 * t.y;
        t = unpk(v0.z); a4 += n0 * t.x; a5 += n0 * t.y;
        t = unpk(v0.w); a6 += n0 * t.x; a7 += n0 * t.y;
        t = unpk(v1.x); a0 += n1 * t.x; a1 += n1 * t.y;
        t = unpk(v1.y); a2 += n1 * t.x; a3 += n1 * t.y;
        t = unpk(v1.z); a4 += n1 * t.x; a5 += n1 * t.y;
        t = unpk(v1.w); a6 += n1 * t.x; a7 += n1 * t.y;
        t = unpk(v2.x); a0 += n2 * t.x; a1 += n2 * t.y;
        t = unpk(v2.y); a2 += n2 * t.x; a3 += n2 * t.y;
        t = unpk(v2.z); a4 += n2 * t.x; a5 += n2 * t.y;
        t = unpk(v2.w); a6 += n2 * t.x; a7 += n2 * t.y;
        t = unpk(v3.x); a0 += n3 * t.x; a1 += n3 * t.y;
        t = unpk(v3.y); a2 += n3 * t.x; a3 += n3 * t.y;
        t = unpk(v3.z); a4 += n3 * t.x; a5 += n3 * t.y;
        t = unpk(v3.w); a6 += n3 * t.x; a7 += n3 * t.y;
    }
    for (; e < e1; ++e) {
        unsigned q0 = __builtin_nontemporal_load(adjc + e);
        uintx4 v0 = src[(q0 & SRCMASK) * 2 + u];
        float n0 = dec_nm(q0);
        float2 t;
        t = unpk(v0.x); a0 += n0 * t.x; a1 += n0 * t.y;
        t = unpk(v0.y); a2 += n0 * t.x; a3 += n0 * t.y;
        t = unpk(v0.z); a4 += n0 * t.x; a5 += n0 * t.y;
        t = unpk(v0.w); a6 += n0 * t.x; a7 += n0 * t.y;
    }
    uintx4 o;
    o.x = pk(a0, a1); o.y = pk(a2, a3); o.z = pk(a4, a5); o.w = pk(a6, a7);
    __builtin_nontemporal_store(o, (uintx4*)(P + (size_t)s * NT8 + (size_t)node * 8) + u);
}

// ---------------- dense transform v6: 512 threads, 128 nodes, 4 nodes/thread ----------------
// Grid NB128 -> 5696 waves (70% device cap). spi/spo/xr all bf16-packed LDS.

template<int FIN, bool PERK, bool LAST>
__global__ __launch_bounds__(512) void k_xform(
    const unsigned* __restrict__ P, const float* __restrict__ xin,
    const float* __restrict__ W, const float* __restrict__ rw,
    const float* __restrict__ bb, unsigned* __restrict__ OUTn,
    float* __restrict__ xm, float* __restrict__ stats) {
    constexpr int ND = 128;
    __shared__ unsigned spi[ND][17];
    __shared__ unsigned spo[LAST ? 1 : ND][LAST ? 1 : 17];
    __shared__ unsigned xr[FIN == 32 ? ND : 1][FIN == 32 ? 17 : 1];
    int tid = threadIdx.x;
    int node0 = blockIdx.x * ND;

    if constexpr (FIN == 32) {
        for (int t4 = tid; t4 < ND * 8; t4 += 512) {   // 2 iters
            int n = t4 >> 3, j = t4 & 7;
            float4 v = ((const float4*)xin)[(size_t)(node0 + n) * 8 + j];
            xr[n][2 * j]     = pk(v.x, v.y);
            xr[n][2 * j + 1] = pk(v.z, v.w);
        }
    }
    if constexpr (!PERK) {
        {
            int t4 = tid;   // 512 uintx4 loads, exactly one per thread
            int s2 = t4 >> 8, r = t4 & 255, n = r >> 1, u4 = (r & 1) * 4;
            uintx4 v = *(const uintx4*)(P + (size_t)s2 * NT8 + (size_t)(node0 + n) * 8 + u4);
            int base = s2 * 8 + u4;
            spi[n][base] = v.x; spi[n][base + 1] = v.y;
            spi[n][base + 2] = v.z; spi[n][base + 3] = v.w;
        }
    }

    int f2 = tid & 15, nl = tid >> 4;      // 32 thread-rows x 4 nodes
    int nbase = nl * 4;
    float2 xv2[4];
    if constexpr (FIN == 2) {
#pragma unroll
        for (int n = 0; n < 4; ++n) xv2[n] = ((const float2*)xin)[node0 + nbase + n];
    }
    float m0[4] = {}, m1[4] = {};

#pragma unroll
    for (int k = 0; k < KS; ++k) {
        __syncthreads();   // spi free (prev compute done) / spo free (prev store done)
        if constexpr (PERK) {
            int t4 = tid;
            int s2 = t4 >> 8, r = t4 & 255, n = r >> 1, u4 = (r & 1) * 4;
            int s = k * 2 + s2;
            uintx4 v = *(const uintx4*)(P + (size_t)s * NT8 + (size_t)(node0 + n) * 8 + u4);
            int base = s2 * 8 + u4;
            spi[n][base] = v.x; spi[n][base + 1] = v.y;
            spi[n][base + 2] = v.z; spi[n][base + 3] = v.w;
        }
        __syncthreads();

        float2 bv = ((const float2*)(bb + k * HID))[f2];
        float h0[4], h1[4];
#pragma unroll
        for (int n = 0; n < 4; ++n) { h0[n] = bv.x; h1[n] = bv.y; }
        const float2* W2 = (const float2*)(W + (size_t)k * HID * HID);
        const float2* R2 = (const float2*)(rw + (size_t)k * FIN * HID);
#pragma unroll 4
        for (int i2 = 0; i2 < 16; ++i2) {
            float2 wf0 = W2[(2 * i2) * 16 + f2];
            float2 wf1 = W2[(2 * i2 + 1) * 16 + f2];
            float2 rf0, rf1;
            if constexpr (FIN == 32) {
                rf0 = R2[(2 * i2) * 16 + f2];
                rf1 = R2[(2 * i2 + 1) * 16 + f2];
            }
#pragma unroll
            for (int n = 0; n < 4; ++n) {
                float2 sv = unpk(spi[nbase + n][i2]);
                h0[n] += sv.x * wf0.x + sv.y * wf1.x;
                h1[n] += sv.x * wf0.y + sv.y * wf1.y;
                if constexpr (FIN == 32) {
                    float2 xq = unpk(xr[nbase + n][i2]);
                    h0[n] += xq.x * rf0.x + xq.y * rf1.x;
                    h1[n] += xq.x * rf0.y + xq.y * rf1.y;
                }
            }
        }
        if constexpr (FIN == 2) {
            float2 r0 = R2[0 * 16 + f2], r1 = R2[1 * 16 + f2];
#pragma unroll
            for (int n = 0; n < 4; ++n) {
                h0[n] += xv2[n].x * r0.x + xv2[n].y * r1.x;
                h1[n] += xv2[n].x * r0.y + xv2[n].y * r1.y;
            }
        }

        if constexpr (LAST) {
#pragma unroll
            for (int n = 0; n < 4; ++n) {
                m0[n] += fmaxf(h0[n], 0.f);
                m1[n] += fmaxf(h1[n], 0.f);
            }
        } else {
#pragma unroll
            for (int n = 0; n < 4; ++n)
                spo[nbase + n][f2] = pk(fmaxf(h0[n], 0.f), fmaxf(h1[n], 0.f));
            __syncthreads();
            {
                int t4 = tid;
                int s2 = t4 >> 8, r = t4 & 255, n = r >> 1, u4 = (r & 1) * 4;
                int so = k * 2 + s2;
                int base = s2 * 8 + u4;
                uintx4 v;
                v.x = spo[n][base]; v.y = spo[n][base + 1];
                v.z = spo[n][base + 2]; v.w = spo[n][base + 3];
                __builtin_nontemporal_store(
                    v, (uintx4*)(OUTn + (size_t)so * NT8 + (size_t)(node0 + n) * 8 + u4));
            }
        }
    }

    if constexpr (LAST) {
        float sv0 = 0.f, sq0 = 0.f, sv1 = 0.f, sq1 = 0.f;
#pragma unroll
        for (int n = 0; n < 4; ++n) {
            float v0 = m0[n] * (1.f / 3.f), v1 = m1[n] * (1.f / 3.f);
            ((float2*)xm)[(size_t)(node0 + nbase + n) * 16 + f2] = make_float2(v0, v1);
            sv0 += v0; sq0 += v0 * v0;
            sv1 += v1; sq1 += v1 * v1;
        }
        float* red = (float*)spi;   // 2048 floats needed; spi has 2176 uints
        __syncthreads();
        red[0 * 512 + f2 * 32 + nl] = sv0;
        red[1 * 512 + f2 * 32 + nl] = sq0;
        __syncthreads();
        if (nl == 0) {
            float a = 0.f, b = 0.f;
#pragma unroll
            for (int j = 0; j < 32; ++j) {
                a += red[0 * 512 + f2 * 32 + j];
                b += red[1 * 512 + f2 * 32 + j];
            }
            atomicAdd(&stats[2 * f2], a);
            atomicAdd(&stats[HID + 2 * f2], b);
        }
        __syncthreads();
        red[0 * 512 + f2 * 32 + nl] = sv1;
        red[1 * 512 + f2 * 32 + nl] = sq1;
        __syncthreads();
        if (nl == 0) {
            float c = 0.f, d = 0.f;
#pragma unroll
            for (int j = 0; j < 32; ++j) {
                c += red[0 * 512 + f2 * 32 + j];
                d += red[1 * 512 + f2 * 32 + j];
            }
            atomicAdd(&stats[2 * f2 + 1], c);
            atomicAdd(&stats[HID + 2 * f2 + 1], d);
        }
    }
}

// ---------------- layer-1 t=0: gather fp32 x (729KB, L2-resident) + dense ----------------

__global__ void k_gath2(const float2* __restrict__ xp, const int* __restrict__ offs,
                        const unsigned* __restrict__ adjc, float2* __restrict__ pag) {
    int node = blockIdx.x * blockDim.x + threadIdx.x;
    if (node >= NTOT) return;
    float a0 = 0.f, a1 = 0.f;
    int e0 = offs[node], e1 = offs[node + 1];
    int e = e0;
    for (; e + 4 <= e1; e += 4) {
        unsigned q0 = __builtin_nontemporal_load(adjc + e);
        unsigned q1 = __builtin_nontemporal_load(adjc + e + 1);
        unsigned q2 = __builtin_nontemporal_load(adjc + e + 2);
        unsigned q3 = __builtin_nontemporal_load(adjc + e + 3);
        float2 x0 = xp[q0 & SRCMASK], x1 = xp[q1 & SRCMASK];
        float2 x2 = xp[q2 & SRCMASK], x3 = xp[q3 & SRCMASK];
        float n0 = dec_nm(q0), n1 = dec_nm(q1), n2 = dec_nm(q2), n3 = dec_nm(q3);
        a0 += n0 * x0.x + n1 * x1.x + n2 * x2.x + n3 * x3.x;
        a1 += n0 * x0.y + n1 * x1.y + n2 * x2.y + n3 * x3.y;
    }
    for (; e < e1; ++e) {
        unsigned q0 = __builtin_nontemporal_load(adjc + e);
        float2 xs = xp[q0 & SRCMASK];
        float nm = dec_nm(q0);
        a0 += nm * xs.x; a1 += nm * xs.y;
    }
    pag[node] = make_float2(a0, a1);
}

__global__ void k_x0(const float2* __restrict__ pag, const float2* __restrict__ xp,
                     const float* __restrict__ iw, const float* __restrict__ rw0,
                     const float* __restrict__ b0, unsigned* __restrict__ OUT) {
    int tid = blockIdx.x * blockDim.x + threadIdx.x;  // NTOT*16
    int f2 = tid & 15;
    int node = tid >> 4;
    float2 pv = pag[node];
    float2 xn = xp[node];
#pragma unroll
    for (int k = 0; k < KS; ++k) {
        const float2* iw2 = (const float2*)(iw + k * 2 * HID);
        const float2* rw2 = (const float2*)(rw0 + k * 2 * HID);
        float2 wi0 = iw2[0 * 16 + f2], wi1 = iw2[1 * 16 + f2];
        float2 wr0 = rw2[0 * 16 + f2], wr1 = rw2[1 * 16 + f2];
        float2 bv = ((const float2*)(b0 + k * HID))[f2];
        float o0 = fmaxf(pv.x * wi0.x + pv.y * wi1.x + xn.x * wr0.x + xn.y * wr1.x + bv.x, 0.f);
        float o1 = fmaxf(pv.x * wi0.y + pv.y * wi1.y + xn.x * wr0.y + xn.y * wr1.y + bv.y, 0.f);
        OUT[(size_t)(k * 2 + (f2 >> 3)) * NT8 + (size_t)node * 8 + (f2 & 7)] = pk(o0, o1);
    }
}

// ---------------- ARMA F=1: hoisted recurrent + fp32 float4 plane ----------------

__global__ void k_rec3(const float* __restrict__ xb, const float* __restrict__ iw3,
                       const float* __restrict__ rw3, const float* __restrict__ b3,
                       float4* __restrict__ H0, float4* __restrict__ RT) {
    int n = blockIdx.x * blockDim.x + threadIdx.x;
    if (n >= NTOT) return;
    float xr[HID];
#pragma unroll
    for (int j = 0; j < 8; ++j) {
        float4 v = ((const float4*)xb)[(size_t)n * 8 + j];
        xr[4 * j] = v.x; xr[4 * j + 1] = v.y; xr[4 * j + 2] = v.z; xr[4 * j + 3] = v.w;
    }
    {
        float a0 = 0.f, a1 = 0.f, a2 = 0.f;
#pragma unroll
        for (int i = 0; i < HID; ++i) {
            a0 += xr[i] * iw3[0 * HID + i];
            a1 += xr[i] * iw3[1 * HID + i];
            a2 += xr[i] * iw3[2 * HID + i];
        }
        H0[n] = make_float4(a0, a1, a2, 0.f);
    }
#pragma unroll
    for (int t = 0; t < TL; ++t) {
        float a0 = b3[t * KS + 0], a1 = b3[t * KS + 1], a2 = b3[t * KS + 2];
        const float* r = rw3 + (size_t)t * KS * HID;
#pragma unroll
        for (int i = 0; i < HID; ++i) {
            a0 += xr[i] * r[0 * HID + i];
            a1 += xr[i] * r[1 * HID + i];
            a2 += xr[i] * r[2 * HID + i];
        }
        RT[(size_t)t * NTOT + n] = make_float4(a0, a1, a2, 0.f);
    }
}

template<bool LAST>
__global__ void k_prop1(const float4* __restrict__ H, const float4* __restrict__ RT,
                        const float* __restrict__ W_t, const int* __restrict__ offs,
                        const unsigned* __restrict__ adjc, const int* __restrict__ perm,
                        float* __restrict__ outp) {
    int node = blockIdx.x * blockDim.x + threadIdx.x;
    if (node >= NTOT) return;
    float4 rt = RT[node];
    float a0 = rt.x, a1 = rt.y, a2 = rt.z;
    int e0 = offs[node], e1 = offs[node + 1];
    int e = e0;
    for (; e + 4 <= e1; e += 4) {
        unsigned q0 = __builtin_nontemporal_load(adjc + e);
        unsigned q1 = __builtin_nontemporal_load(adjc + e + 1);
        unsigned q2 = __builtin_nontemporal_load(adjc + e + 2);
        unsigned q3 = __builtin_nontemporal_load(adjc + e + 3);
        float4 h0 = H[q0 & SRCMASK], h1 = H[q1 & SRCMASK];
        float4 h2 = H[q2 & SRCMASK], h3 = H[q3 & SRCMASK];
        float n0 = dec_nm(q0), n1 = dec_nm(q1), n2 = dec_nm(q2), n3 = dec_nm(q3);
        a0 += n0 * h0.x; a1 += n0 * h0.y; a2 += n0 * h0.z;
        a0 += n1 * h1.x; a1 += n1 * h1.y; a2 += n1 * h1.z;
        a0 += n2 * h2.x; a1 += n2 * h2.y; a2 += n2 * h2.z;
        a0 += n3 * h3.x; a1 += n3 * h3.y; a2 += n3 * h3.z;
    }
    for (; e < e1; ++e) {
        unsigned q0 = __builtin_nontemporal_load(adjc + e);
        float4 h = H[q0 & SRCMASK];
        float nm = dec_nm(q0);
        a0 += nm * h.x; a1 += nm * h.y; a2 += nm * h.z;
    }
    a0 = fmaxf(a0, 0.f); a1 = fmaxf(a1, 0.f); a2 = fmaxf(a2, 0.f);
    if constexpr (LAST) {
        outp[perm[node]] = (a0 + a1 + a2) * (1.f / 3.f);
    } else {
        ((float4*)outp)[node] = make_float4(a0 * W_t[0], a1 * W_t[1], a2 * W_t[2], 0.f);
    }
}

// ---------------- batchnorm (+relu) ----------------

__global__ void k_bnstats(const float* __restrict__ x, float* __restrict__ stats, int F) {
    __shared__ float s1[256];
    __shared__ float s2[256];
    int tid = threadIdx.x;
    int gid = blockIdx.x * blockDim.x + tid;
    int stride = gridDim.x * blockDim.x;
    int total = NTOT * F;
    float a = 0.f, b = 0.f;
    for (int i = gid; i < total; i += stride) {
        float v = x[i];
        a += v;
        b += v * v;
    }
    s1[tid] = a; s2[tid] = b;
    __syncthreads();
    for (int s = 128; s >= F; s >>= 1) {
        if (tid < s) { s1[tid] += s1[tid + s]; s2[tid] += s2[tid + s]; }
        __syncthreads();
    }
    if (tid < F) {
        atomicAdd(&stats[tid], s1[tid]);
        atomicAdd(&stats[F + tid], s2[tid]);
    }
}

__global__ void k_bnapply32(float* __restrict__ x, const float* __restrict__ stats,
                            const float* __restrict__ g, const float* __restrict__ be,
                            unsigned* __restrict__ xbf) {
    int tid = blockIdx.x * blockDim.x + threadIdx.x;   // NTOT*16
    int f2 = tid & 15;
    int node = tid >> 4;
    int f0 = 2 * f2, f1 = f0 + 1;
    float mm0 = stats[f0] * (1.f / NTOT);
    float vv0 = stats[HID + f0] * (1.f / NTOT) - mm0 * mm0;
    float mm1 = stats[f1] * (1.f / NTOT);
    float vv1 = stats[HID + f1] * (1.f / NTOT) - mm1 * mm1;
    float y0 = fmaxf((x[(size_t)node * 32 + f0] - mm0) * rsqrtf(vv0 + EPSV) * g[f0] + be[f0], 0.f);
    float y1 = fmaxf((x[(size_t)node * 32 + f1] - mm1) * rsqrtf(vv1 + EPSV) * g[f1] + be[f1], 0.f);
    x[(size_t)node * 32 + f0] = y0;
    x[(size_t)node * 32 + f1] = y1;
    if (xbf) xbf[(size_t)(f2 >> 3) * NT8 + (size_t)node * 8 + (f2 & 7)] = pk(y0, y1);
}

__global__ void k_bnapply1(float* __restrict__ x, const float* __restrict__ stats,
                           const float* __restrict__ g, const float* __restrict__ be) {
    int i = blockIdx.x * blockDim.x + threadIdx.x;
    if (i >= NTOT) return;
    float m = stats[0] * (1.f / NTOT);
    float v = stats[1] * (1.f / NTOT) - m * m;
    float y = (x[i] - m) * rsqrtf(v + EPSV) * g[0] + be[0];
    x[i] = fmaxf(y, 0.f);
}

// ---------------- classifier + per-graph max ----------------

__global__ void k_final(const float* __restrict__ h, const float* __restrict__ cw,
                        const float* __restrict__ cb, float* __restrict__ out) {
    __shared__ float smax[256];
    int g = blockIdx.x;
    float cwv = cw[0], cbv = cb[0];
    float mx = -INFINITY;
    for (int i = threadIdx.x; i < NUM_NODES; i += blockDim.x) {
        int nidx = g * NUM_NODES + i;
        float v = h[nidx] * cwv + cbv;
        out[nidx] = v;
        mx = fmaxf(mx, v);
    }
    smax[threadIdx.x] = mx;
    __syncthreads();
    for (int s = 128; s >= 1; s >>= 1) {
        if (threadIdx.x < s) smax[threadIdx.x] = fmaxf(smax[threadIdx.x], smax[threadIdx.x + s]);
        __syncthreads();
    }
    if (threadIdx.x == 0) out[NTOT + g] = smax[0];
}

// ---------------- host launch ----------------

extern "C" void kernel_launch(void* const* d_in, const int* in_sizes, int n_in,
                              void* d_out, int out_size, void* d_ws, size_t ws_size,
                              hipStream_t stream) {
    const float* x   = (const float*)d_in[0];
    const int*   ei  = (const int*)d_in[1];
    const int*   row = ei;
    const int*   col = ei + NE;
    const float* wts = (const float*)d_in[2];
    const float* iw1 = (const float*)d_in[4];
    const float* w1  = (const float*)d_in[5];
    const float* rw1 = (const float*)d_in[6];
    const float* b1  = (const float*)d_in[7];
    const float* g1  = (const float*)d_in[8];
    const float* be1 = (const float*)d_in[9];
    const float* iw2 = (const float*)d_in[10];
    const float* w2  = (const float*)d_in[11];
    const float* rw2 = (const float*)d_in[12];
    const float* b2  = (const float*)d_in[13];
    const float* g2  = (const float*)d_in[14];
    const float* be2 = (const float*)d_in[15];
    const float* iw3 = (const float*)d_in[16];
    const float* w3  = (const float*)d_in[17];
    const float* rw3 = (const float*)d_in[18];
    const float* b3  = (const float*)d_in[19];
    const float* g3  = (const float*)d_in[20];
    const float* be3 = (const float*)d_in[21];
    const float* cw  = (const float*)d_in[22];
    const float* cb  = (const float*)d_in[23];
    float* out = (float*)d_out;

    char* p = (char*)d_ws;
    auto alloc = [&](size_t bytes) {
        char* r = p;
        p += (bytes + 255) & ~(size_t)255;
        return r;
    };
    // contiguous zero range: indegS, cnt, stats
    int*      indegS = (int*)alloc((size_t)NTOT * 16);
    int*      cnt    = (int*)alloc((size_t)CNTN * 4);
    float*    stats  = (float*)alloc(3 * 2 * HID * 4);
    char*     zend   = p;
    int*      indeg  = (int*)alloc((size_t)NTOT * 4);
    int*      bsum   = (int*)alloc((size_t)NBLK * 4);
    int*      offs   = (int*)alloc((size_t)(NTOT + 1) * 4);
    int*      cursor = (int*)alloc((size_t)NTOT * 4);
    int*      perm   = (int*)alloc((size_t)NTOT * 4);
    int*      invperm= (int*)alloc((size_t)NTOT * 4);
    int*      indegp = (int*)alloc((size_t)NTOT * 4);
    float*    disp   = (float*)alloc((size_t)NTOT * 4);
    unsigned* adjc   = (unsigned*)alloc((size_t)NE * 4);
    unsigned* OUTA   = (unsigned*)alloc((size_t)6 * NT8 * 4);   // 17.5MB
    unsigned* OUTB   = (unsigned*)alloc((size_t)6 * NT8 * 4);
    unsigned* P      = (unsigned*)alloc((size_t)6 * NT8 * 4);
    unsigned* xplane = (unsigned*)alloc((size_t)2 * NT8 * 4);   // 5.8MB
    float2*   xp     = (float2*)alloc((size_t)NTOT * 8);
    float2*   pag    = (float2*)alloc((size_t)NTOT * 8);
    float*    xa     = (float*)alloc((size_t)NTOT * HID * 4);
    float*    xb     = (float*)alloc((size_t)NTOT * HID * 4);
    float*    xc     = (float*)alloc((size_t)NTOT * 4);
    float4*   RT     = (float4*)alloc((size_t)TL * NTOT * 16);  // 7.3MB
    if ((size_t)(p - (char*)d_ws) > ws_size) return;

    const int tb = 256;
    const int ebl = (NE + tb - 1) / tb;
    const int nbl = NTOT / tb;           // 356
    const int g16 = NTOT * 16 / tb;      // 5696

    hipMemsetAsync(indegS, 0, (size_t)(zend - (char*)indegS), stream);

    k_cnt<<<ebl, tb, 0, stream>>>(col, indegS);
    k_merge<<<nbl, tb, 0, stream>>>(indegS, indeg);
    k_lhist<<<NBLK, SCAN_B, 0, stream>>>(indeg, cnt);
    k_scan1<<<CNTB, SCAN_B, 0, stream>>>(cnt, bsum);
    k_scan2<<<1, 512, 0, stream>>>(bsum, CNTB);
    k_scan3<<<CNTB, SCAN_B, 0, stream>>>(cnt, bsum, cnt, -1, 0);
    k_rank<<<NBLK, SCAN_B, 0, stream>>>(indeg, cnt, perm, invperm, indegp);
    k_xp<<<nbl, tb, 0, stream>>>((const float2*)x, perm, xp);
    k_scan1<<<NBLK, SCAN_B, 0, stream>>>(indegp, bsum);
    k_scan2<<<1, 512, 0, stream>>>(bsum, NBLK);
    k_scan3<<<NBLK, SCAN_B, 0, stream>>>(indegp, bsum, offs, NTOT, NE);
    hipMemcpyAsync(cursor, offs, (size_t)NTOT * 4, hipMemcpyDeviceToDevice, stream);
    k_fill<<<ebl, tb, 0, stream>>>(row, col, wts, invperm, cursor, adjc);
    k_degdis<<<nbl, tb, 0, stream>>>(adjc, offs, disp);
    k_norm<<<nbl, tb, 0, stream>>>(adjc, offs, disp);

    // ---- layer 1: 2 -> 32 ----
    {
        k_gath2<<<nbl, tb, 0, stream>>>(xp, offs, adjc, pag);
        k_x0<<<g16, tb, 0, stream>>>(pag, xp, iw1, rw1, b1, OUTA);
        unsigned* Hc = OUTA; unsigned* Hn = OUTB;
        for (int t = 1; t < TL - 1; ++t) {
            k_gath<<<6 * NB128, tb, 0, stream>>>(Hc, offs, adjc, P);
            k_xform<2, true, false><<<NB128, 512, 0, stream>>>(
                P, (const float*)xp, w1 + (size_t)(t - 1) * KS * HID * HID,
                rw1 + (size_t)t * KS * 2 * HID, b1 + (size_t)t * KS * HID, Hn,
                nullptr, nullptr);
            unsigned* tmp = Hc; Hc = Hn; Hn = tmp;
        }
        k_gath<<<6 * NB128, tb, 0, stream>>>(Hc, offs, adjc, P);
        k_xform<2, true, true><<<NB128, 512, 0, stream>>>(
            P, (const float*)xp, w1 + (size_t)(TL - 2) * KS * HID * HID,
            rw1 + (size_t)(TL - 1) * KS * 2 * HID, b1 + (size_t)(TL - 1) * KS * HID,
            nullptr, xa, stats);
        k_bnapply32<<<g16, tb, 0, stream>>>(xa, stats, g1, be1, xplane);
    }
    // ---- layer 2: 32 -> 32 ----
    {
        k_gath<<<2 * NB128, tb, 0, stream>>>(xplane, offs, adjc, P);
        k_xform<32, false, false><<<NB128, 512, 0, stream>>>(
            P, xa, iw2, rw2, b2, OUTA, nullptr, nullptr);
        unsigned* Hc = OUTA; unsigned* Hn = OUTB;
        for (int t = 1; t < TL - 1; ++t) {
            k_gath<<<6 * NB128, tb, 0, stream>>>(Hc, offs, adjc, P);
            k_xform<32, true, false><<<NB128, 512, 0, stream>>>(
                P, xa, w2 + (size_t)(t - 1) * KS * HID * HID,
                rw2 + (size_t)t * KS * HID * HID, b2 + (size_t)t * KS * HID, Hn,
                nullptr, nullptr);
            unsigned* tmp = Hc; Hc = Hn; Hn = tmp;
        }
        k_gath<<<6 * NB128, tb, 0, stream>>>(Hc, offs, adjc, P);
        k_xform<32, true, true><<<NB128, 512, 0, stream>>>(
            P, xa, w2 + (size_t)(TL - 2) * KS * HID * HID,
            rw2 + (size_t)(TL - 1) * KS * HID * HID, b2 + (size_t)(TL - 1) * KS * HID,
            nullptr, xb, stats + 2 * HID);
        k_bnapply32<<<g16, tb, 0, stream>>>(xb, stats + 2 * HID, g2, be2, nullptr);
    }
    // ---- layer 3: 32 -> 1 ----
    {
        float4* HAf = (float4*)OUTA;
        float4* HBf = (float4*)OUTB;
        k_rec3<<<nbl, tb, 0, stream>>>(xb, iw3, rw3, b3, HAf, RT);
        const float4* Hc = HAf; float4* Hn = HBf;
        for (int t = 0; t < TL - 1; ++t) {
            k_prop1<false><<<nbl, tb, 0, stream>>>(
                Hc, RT + (size_t)t * NTOT, w3 + (size_t)t * KS, offs, adjc, perm, (float*)Hn);
            const float4* tmp = Hc; Hc = Hn; Hn = (float4*)tmp;
        }
        k_prop1<true><<<nbl, tb, 0, stream>>>(
            Hc, RT + (size_t)(TL - 1) * NTOT, nullptr, offs, adjc, perm, xc);
        k_bnstats<<<256, tb, 0, stream>>>(xc, stats + 4 * HID, 1);
        k_bnapply1<<<nbl, tb, 0, stream>>>(xc, stats + 4 * HID, g3, be3);
    }

    k_final<<<N_GRAPHS, 256, 0, stream>>>(xc, cw, cb, out);
}

// Round 15
// 1120.486 us; speedup vs baseline: 1.1085x; 1.1085x over previous
//
#include <hip/hip_runtime.h>
#include <hip/hip_fp16.h>

#define N_GRAPHS 32
#define NUM_NODES 2848
#define NTOT (N_GRAPHS * NUM_NODES)   // 91136
#define NE 1000000
#define KS 3
#define TL 5
#define HID 32
#define EPSV 1e-5f
#define SCAN_B 256
#define NBLK (NTOT / SCAN_B)          // 356 (exact)
#define NBINS 64
#define CNTN (NBINS * NBLK)           // 22784
#define CNTB (CNTN / SCAN_B)          // 89
#define NT8 (NTOT * 8)                // uints per section ([NTOT][8] uints = 2.9MB)
#define NB128 (NTOT / 128)            // 712
#define SRCMASK 0x1FFFFu

typedef unsigned uintx4 __attribute__((ext_vector_type(4)));

// ---------------- bf16 / fp15 helpers ----------------

__device__ __forceinline__ float2 unpk(unsigned u) {
    return make_float2(__uint_as_float(u << 16), __uint_as_float(u & 0xffff0000u));
}
__device__ __forceinline__ unsigned bf16rn(float f) {
    unsigned x = __float_as_uint(f);
    return (x + 0x7fffu + ((x >> 16) & 1u)) >> 16;
}
__device__ __forceinline__ unsigned pk(float a, float b) {
    return bf16rn(a) | (bf16rn(b) << 16);
}
__device__ __forceinline__ float dec_nm(unsigned q) {
    return __half2float(__ushort_as_half((unsigned short)(q >> 17)));
}

// ---------------- graph preprocessing ----------------

__global__ void k_cnt(const int* __restrict__ col, int* __restrict__ indegS) {
    int e = blockIdx.x * blockDim.x + threadIdx.x;
    if (e < NE) atomicAdd(&indegS[(col[e] << 2) | (e & 3)], 1);
}

__global__ void k_merge(const int* __restrict__ indegS, int* __restrict__ indeg) {
    int n = blockIdx.x * blockDim.x + threadIdx.x;
    if (n < NTOT) {
        int4 v = ((const int4*)indegS)[n];
        indeg[n] = v.x + v.y + v.z + v.w;
    }
}

__global__ void k_lhist(const int* __restrict__ indeg, int* __restrict__ cnt) {
    __shared__ int h[NBINS];
    int t = threadIdx.x;
    if (t < NBINS) h[t] = 0;
    __syncthreads();
    int n = blockIdx.x * SCAN_B + t;
    atomicAdd(&h[min(indeg[n], NBINS - 1)], 1);
    __syncthreads();
    if (t < NBINS) cnt[t * NBLK + blockIdx.x] = h[t];
}

__global__ void k_scan1(const int* __restrict__ in, int* __restrict__ bsum) {
    __shared__ int s[SCAN_B];
    int i = blockIdx.x * SCAN_B + threadIdx.x;
    s[threadIdx.x] = in[i];
    __syncthreads();
    for (int st = SCAN_B / 2; st >= 1; st >>= 1) {
        if (threadIdx.x < st) s[threadIdx.x] += s[threadIdx.x + st];
        __syncthreads();
    }
    if (threadIdx.x == 0) bsum[blockIdx.x] = s[0];
}

__global__ void k_scan2(int* __restrict__ bsum, int n) {
    __shared__ int s[512];
    int t = threadIdx.x;
    int v = (t < n) ? bsum[t] : 0;
    s[t] = v;
    __syncthreads();
    for (int off = 1; off < 512; off <<= 1) {
        int a = (t >= off) ? s[t - off] : 0;
        __syncthreads();
        s[t] += a;
        __syncthreads();
    }
    if (t < n) bsum[t] = s[t] - v;   // exclusive
}

__global__ void k_scan3(const int* __restrict__ in, const int* __restrict__ bsum,
                        int* __restrict__ out, int sentIdx, int sentVal) {
    __shared__ int s[SCAN_B];
    int i = blockIdx.x * SCAN_B + threadIdx.x;
    int v = in[i];
    s[threadIdx.x] = v;
    __syncthreads();
    for (int off = 1; off < SCAN_B; off <<= 1) {
        int a = (threadIdx.x >= off) ? s[threadIdx.x - off] : 0;
        __syncthreads();
        s[threadIdx.x] += a;
        __syncthreads();
    }
    out[i] = bsum[blockIdx.x] + s[threadIdx.x] - v;
    if (i == 0 && sentIdx >= 0) out[sentIdx] = sentVal;
}

__global__ void k_rank(const int* __restrict__ indeg, const int* __restrict__ cnt,
                       int* __restrict__ perm, int* __restrict__ invperm,
                       int* __restrict__ indegp) {
    __shared__ int base[NBINS];
    __shared__ int cur[NBINS];
    int t = threadIdx.x;
    if (t < NBINS) { base[t] = cnt[t * NBLK + blockIdx.x]; cur[t] = 0; }
    __syncthreads();
    int n = blockIdx.x * SCAN_B + t;
    int dg = indeg[n];
    int b = min(dg, NBINS - 1);
    int pos = base[b] + atomicAdd(&cur[b], 1);
    perm[pos] = n;
    invperm[n] = pos;
    indegp[pos] = dg;
}

__global__ void k_xp(const float2* __restrict__ x, const int* __restrict__ perm,
                     float2* __restrict__ xp) {
    int i = blockIdx.x * blockDim.x + threadIdx.x;
    if (i < NTOT) xp[i] = x[perm[i]];
}

__global__ void k_fill(const int* __restrict__ row, const int* __restrict__ col,
                       const float* __restrict__ w, const int* __restrict__ invperm,
                       int* __restrict__ cursor, unsigned* __restrict__ adjc) {
    int e = blockIdx.x * blockDim.x + threadIdx.x;
    if (e < NE) {
        int pr = invperm[row[e]], pc = invperm[col[e]];
        int p = atomicAdd(&cursor[pc], 1);
        unsigned short hb = __half_as_ushort(__float2half(w[e]));   // sign bit = 0
        adjc[p] = ((unsigned)hb << 17) | (unsigned)pr;
    }
}

__global__ void k_degdis(const unsigned* __restrict__ adjc, const int* __restrict__ offs,
                         float* __restrict__ disp) {
    int n = blockIdx.x * blockDim.x + threadIdx.x;
    if (n >= NTOT) return;
    int e0 = offs[n], e1 = offs[n + 1];
    float d = 0.f;
    for (int e = e0; e < e1; ++e) d += dec_nm(adjc[e]);
    disp[n] = (d > 0.f) ? rsqrtf(d) : 0.f;
}

__global__ void k_norm(unsigned* __restrict__ adjc, const int* __restrict__ offs,
                       const float* __restrict__ disp) {
    int n = blockIdx.x * blockDim.x + threadIdx.x;
    if (n >= NTOT) return;
    float dc = disp[n];
    int e0 = offs[n], e1 = offs[n + 1];
    for (int e = e0; e < e1; ++e) {
        unsigned q = adjc[e];
        float nm = dc * dec_nm(q) * disp[q & SRCMASK];
        unsigned short hb = __half_as_ushort(__float2half(nm));
        adjc[e] = ((unsigned)hb << 17) | (q & SRCMASK);
    }
}

// ---------------- sectioned gather (R9 version, proven 68us) ----------------

__global__ __launch_bounds__(256) void k_gath(
    const unsigned* __restrict__ SRC, const int* __restrict__ offs,
    const unsigned* __restrict__ adjc, unsigned* __restrict__ P) {
    int tid = threadIdx.x;
    int u = tid & 1;
    int nl = tid >> 1;               // 0..127
    int bid = blockIdx.x;
    int s = bid / NB128;
    int node = (bid - s * NB128) * 128 + nl;
    const uintx4* src = (const uintx4*)(SRC + (size_t)s * NT8);
    float a0 = 0.f, a1 = 0.f, a2 = 0.f, a3 = 0.f, a4 = 0.f, a5 = 0.f, a6 = 0.f, a7 = 0.f;
    int e0 = offs[node], e1 = offs[node + 1];
    int e = e0;
    for (; e + 4 <= e1; e += 4) {
        unsigned q0 = __builtin_nontemporal_load(adjc + e);
        unsigned q1 = __builtin_nontemporal_load(adjc + e + 1);
        unsigned q2 = __builtin_nontemporal_load(adjc + e + 2);
        unsigned q3 = __builtin_nontemporal_load(adjc + e + 3);
        uintx4 v0 = src[(q0 & SRCMASK) * 2 + u];
        uintx4 v1 = src[(q1 & SRCMASK) * 2 + u];
        uintx4 v2 = src[(q2 & SRCMASK) * 2 + u];
        uintx4 v3 = src[(q3 & SRCMASK) * 2 + u];
        float n0 = dec_nm(q0), n1 = dec_nm(q1), n2 = dec_nm(q2), n3 = dec_nm(q3);
        float2 t;
        t = unpk(v0.x); a0 += n0 * t.x; a1 += n0 * t.y;
        t = unpk(v0.y); a2 += n0 * t.x; a3 += n0 * t.y;
        t = unpk(v0.z); a4 += n0 * t.x; a5 += n0 * t.y;
        t = unpk(v0.w); a6 += n0 * t.x; a7 += n0 * t.y;
        t = unpk(v1.x); a0 += n1 * t.x; a1 += n1 * t.y;
        t = unpk(v1.y); a2 += n1 * t.x; a3 += n1 * t.y;
        t = unpk(v1.z); a4 += n1 * t.x; a5 += n1 * t.y;
        t = unpk(v1.w); a6 += n1 * t.x; a7 += n1 * t.y;
        t = unpk(v2.x); a0 += n2 * t.x; a1 += n2 * t.y;
        t = unpk(v2.y); a2 += n2 * t.x; a3 += n2 * t.y;
        t = unpk(v2.z); a4 += n2 * t.x; a5 += n2 * t.y;
        t = unpk(v2.w); a6 += n2 * t.x; a7 += n2 * t.y;
        t = unpk(v3.x); a0 += n3 * t.x; a1 += n3 * t.y;
        t = unpk(v3.y); a2 += n3 * t.x; a3 += n3 * t.y;
        t = unpk(v3.z); a4 += n3 * t.x; a5 += n3 * t.y;
        t = unpk(v3.w); a6 += n3 * t.x; a7 += n3 * t.y;
    }
    for (; e < e1; ++e) {
        unsigned q0 = __builtin_nontemporal_load(adjc + e);
        uintx4 v0 = src[(q0 & SRCMASK) * 2 + u];
        float n0 = dec_nm(q0);
        float2 t;
        t = unpk(v0.x); a0 += n0 * t.x; a1 += n0 * t.y;
        t = unpk(v0.y); a2 += n0 * t.x; a3 += n0 * t.y;
        t = unpk(v0.z); a4 += n0 * t.x; a5 += n0 * t.y;
        t = unpk(v0.w); a6 += n0 * t.x; a7 += n0 * t.y;
    }
    uintx4 o;
    o.x = pk(a0, a1); o.y = pk(a2, a3); o.z = pk(a4, a5); o.w = pk(a6, a7);
    __builtin_nontemporal_store(o, (uintx4*)(P + (size_t)s * NT8 + (size_t)node * 8) + u);
}

// ---------------- dense transform v7: ONE k PER BLOCK ----------------
// grid = 3*NB128 (2136 blocks), 256 threads, 128 nodes/block, 8 nodes/thread.
// sp fp32 [128][33] (+bf16 xr for FIN=32) = 25.6KB -> 6 blocks/CU.
// SHARED: read sections 0,1 (k-shared input); else sections k*2, k*2+1.
// LAST: write fp32 per-k plane (mean+stats done by k_meanstats).

template<int FIN, bool SHARED, bool LAST>
__global__ __launch_bounds__(256) void k_xformk(
    const unsigned* __restrict__ P, const float* __restrict__ xin,
    const float* __restrict__ W, const float* __restrict__ rw,
    const float* __restrict__ bb, void* __restrict__ outp) {
    __shared__ float sp[128][33];
    __shared__ unsigned xr[FIN == 32 ? 128 : 1][FIN == 32 ? 17 : 1];
    int tid = threadIdx.x;
    int bid = blockIdx.x;
    int k = bid / NB128;
    int node0 = (bid - k * NB128) * 128;
    int sbase = SHARED ? 0 : k * 2;

    for (int t4 = tid; t4 < 512; t4 += 256) {
        int s2 = t4 >> 8, r = t4 & 255, n = r >> 1, u4 = (r & 1) * 4;
        uintx4 v = *(const uintx4*)(P + (size_t)(sbase + s2) * NT8 +
                                    (size_t)(node0 + n) * 8 + u4);
        int base = s2 * 16 + u4 * 2;
        float2 t;
        t = unpk(v.x); sp[n][base]     = t.x; sp[n][base + 1] = t.y;
        t = unpk(v.y); sp[n][base + 2] = t.x; sp[n][base + 3] = t.y;
        t = unpk(v.z); sp[n][base + 4] = t.x; sp[n][base + 5] = t.y;
        t = unpk(v.w); sp[n][base + 6] = t.x; sp[n][base + 7] = t.y;
    }
    if constexpr (FIN == 32) {
        for (int t4 = tid; t4 < 128 * 8; t4 += 256) {
            int n = t4 >> 3, j = t4 & 7;
            float4 v = ((const float4*)xin)[(size_t)(node0 + n) * 8 + j];
            xr[n][2 * j]     = pk(v.x, v.y);
            xr[n][2 * j + 1] = pk(v.z, v.w);
        }
    }
    __syncthreads();

    int f2 = tid & 15, nl = tid >> 4;   // 16 rows x 8 nodes
    int nbase = nl * 8;
    float2 xv2[FIN == 2 ? 8 : 1];
    if constexpr (FIN == 2) {
#pragma unroll
        for (int n = 0; n < 8; ++n) xv2[n] = ((const float2*)xin)[node0 + nbase + n];
    }
    const float2* W2 = (const float2*)(W + (size_t)k * HID * HID);
    const float2* R2 = (const float2*)(rw + (size_t)k * FIN * HID);
    float2 bv = ((const float2*)(bb + k * HID))[f2];
    float h0[8], h1[8];
#pragma unroll
    for (int n = 0; n < 8; ++n) { h0[n] = bv.x; h1[n] = bv.y; }

#pragma unroll 4
    for (int i2 = 0; i2 < 16; ++i2) {
        float2 wf0 = W2[(2 * i2) * 16 + f2];
        float2 wf1 = W2[(2 * i2 + 1) * 16 + f2];
        float2 rf0, rf1;
        if constexpr (FIN == 32) {
            rf0 = R2[(2 * i2) * 16 + f2];
            rf1 = R2[(2 * i2 + 1) * 16 + f2];
        }
#pragma unroll
        for (int n = 0; n < 8; ++n) {
            float s0 = sp[nbase + n][2 * i2];
            float s1 = sp[nbase + n][2 * i2 + 1];
            h0[n] += s0 * wf0.x + s1 * wf1.x;
            h1[n] += s0 * wf0.y + s1 * wf1.y;
            if constexpr (FIN == 32) {
                float2 xq = unpk(xr[nbase + n][i2]);
                h0[n] += xq.x * rf0.x + xq.y * rf1.x;
                h1[n] += xq.x * rf0.y + xq.y * rf1.y;
            }
        }
    }
    if constexpr (FIN == 2) {
        float2 r0 = R2[0 * 16 + f2], r1 = R2[1 * 16 + f2];
#pragma unroll
        for (int n = 0; n < 8; ++n) {
            h0[n] += xv2[n].x * r0.x + xv2[n].y * r1.x;
            h1[n] += xv2[n].x * r0.y + xv2[n].y * r1.y;
        }
    }

    if constexpr (LAST) {
        float2* xo = (float2*)outp + (size_t)k * (NTOT * 16);
#pragma unroll
        for (int n = 0; n < 8; ++n)
            xo[(size_t)(node0 + nbase + n) * 16 + f2] =
                make_float2(fmaxf(h0[n], 0.f), fmaxf(h1[n], 0.f));
    } else {
        unsigned* O = (unsigned*)outp;
#pragma unroll
        for (int n = 0; n < 8; ++n)
            O[(size_t)(k * 2 + (f2 >> 3)) * NT8 + (size_t)(node0 + nbase + n) * 8 +
              (f2 & 7)] = pk(fmaxf(h0[n], 0.f), fmaxf(h1[n], 0.f));
    }
}

// mean over 3 fp32 k-planes -> xm, fused BN partial sums
__global__ void k_meanstats(const float* __restrict__ x0, const float* __restrict__ x1,
                            const float* __restrict__ x2, float* __restrict__ xm,
                            float* __restrict__ stats) {
    __shared__ float s1[256];
    __shared__ float s2[256];
    int tid = threadIdx.x;
    int gid = blockIdx.x * blockDim.x + tid;
    int stride = gridDim.x * blockDim.x;   // multiple of 32
    float a = 0.f, b = 0.f;
    for (int i = gid; i < NTOT * HID; i += stride) {
        float v = (x0[i] + x1[i] + x2[i]) * (1.f / 3.f);
        xm[i] = v;
        a += v;
        b += v * v;
    }
    s1[tid] = a; s2[tid] = b;
    __syncthreads();
    for (int s = 128; s >= HID; s >>= 1) {
        if (tid < s) { s1[tid] += s1[tid + s]; s2[tid] += s2[tid + s]; }
        __syncthreads();
    }
    if (tid < HID) {
        atomicAdd(&stats[tid], s1[tid]);
        atomicAdd(&stats[HID + tid], s2[tid]);
    }
}

// ---------------- layer-1 t=0: gather fp32 x (729KB, L2-resident) + dense ----------------

__global__ void k_gath2(const float2* __restrict__ xp, const int* __restrict__ offs,
                        const unsigned* __restrict__ adjc, float2* __restrict__ pag) {
    int node = blockIdx.x * blockDim.x + threadIdx.x;
    if (node >= NTOT) return;
    float a0 = 0.f, a1 = 0.f;
    int e0 = offs[node], e1 = offs[node + 1];
    int e = e0;
    for (; e + 4 <= e1; e += 4) {
        unsigned q0 = __builtin_nontemporal_load(adjc + e);
        unsigned q1 = __builtin_nontemporal_load(adjc + e + 1);
        unsigned q2 = __builtin_nontemporal_load(adjc + e + 2);
        unsigned q3 = __builtin_nontemporal_load(adjc + e + 3);
        float2 x0 = xp[q0 & SRCMASK], x1 = xp[q1 & SRCMASK];
        float2 x2 = xp[q2 & SRCMASK], x3 = xp[q3 & SRCMASK];
        float n0 = dec_nm(q0), n1 = dec_nm(q1), n2 = dec_nm(q2), n3 = dec_nm(q3);
        a0 += n0 * x0.x + n1 * x1.x + n2 * x2.x + n3 * x3.x;
        a1 += n0 * x0.y + n1 * x1.y + n2 * x2.y + n3 * x3.y;
    }
    for (; e < e1; ++e) {
        unsigned q0 = __builtin_nontemporal_load(adjc + e);
        float2 xs = xp[q0 & SRCMASK];
        float nm = dec_nm(q0);
        a0 += nm * xs.x; a1 += nm * xs.y;
    }
    pag[node] = make_float2(a0, a1);
}

__global__ void k_x0(const float2* __restrict__ pag, const float2* __restrict__ xp,
                     const float* __restrict__ iw, const float* __restrict__ rw0,
                     const float* __restrict__ b0, unsigned* __restrict__ OUT) {
    int tid = blockIdx.x * blockDim.x + threadIdx.x;  // NTOT*16
    int f2 = tid & 15;
    int node = tid >> 4;
    float2 pv = pag[node];
    float2 xn = xp[node];
#pragma unroll
    for (int k = 0; k < KS; ++k) {
        const float2* iw2 = (const float2*)(iw + k * 2 * HID);
        const float2* rw2 = (const float2*)(rw0 + k * 2 * HID);
        float2 wi0 = iw2[0 * 16 + f2], wi1 = iw2[1 * 16 + f2];
        float2 wr0 = rw2[0 * 16 + f2], wr1 = rw2[1 * 16 + f2];
        float2 bv = ((const float2*)(b0 + k * HID))[f2];
        float o0 = fmaxf(pv.x * wi0.x + pv.y * wi1.x + xn.x * wr0.x + xn.y * wr1.x + bv.x, 0.f);
        float o1 = fmaxf(pv.x * wi0.y + pv.y * wi1.y + xn.x * wr0.y + xn.y * wr1.y + bv.y, 0.f);
        OUT[(size_t)(k * 2 + (f2 >> 3)) * NT8 + (size_t)node * 8 + (f2 & 7)] = pk(o0, o1);
    }
}

// ---------------- ARMA F=1: hoisted recurrent + fp32 float4 plane ----------------

__global__ void k_rec3(const float* __restrict__ xb, const float* __restrict__ iw3,
                       const float* __restrict__ rw3, const float* __restrict__ b3,
                       float4* __restrict__ H0, float4* __restrict__ RT) {
    int n = blockIdx.x * blockDim.x + threadIdx.x;
    if (n >= NTOT) return;
    float xr[HID];
#pragma unroll
    for (int j = 0; j < 8; ++j) {
        float4 v = ((const float4*)xb)[(size_t)n * 8 + j];
        xr[4 * j] = v.x; xr[4 * j + 1] = v.y; xr[4 * j + 2] = v.z; xr[4 * j + 3] = v.w;
    }
    {
        float a0 = 0.f, a1 = 0.f, a2 = 0.f;
#pragma unroll
        for (int i = 0; i < HID; ++i) {
            a0 += xr[i] * iw3[0 * HID + i];
            a1 += xr[i] * iw3[1 * HID + i];
            a2 += xr[i] * iw3[2 * HID + i];
        }
        H0[n] = make_float4(a0, a1, a2, 0.f);
    }
#pragma unroll
    for (int t = 0; t < TL; ++t) {
        float a0 = b3[t * KS + 0], a1 = b3[t * KS + 1], a2 = b3[t * KS + 2];
        const float* r = rw3 + (size_t)t * KS * HID;
#pragma unroll
        for (int i = 0; i < HID; ++i) {
            a0 += xr[i] * r[0 * HID + i];
            a1 += xr[i] * r[1 * HID + i];
            a2 += xr[i] * r[2 * HID + i];
        }
        RT[(size_t)t * NTOT + n] = make_float4(a0, a1, a2, 0.f);
    }
}

template<bool LAST>
__global__ void k_prop1(const float4* __restrict__ H, const float4* __restrict__ RT,
                        const float* __restrict__ W_t, const int* __restrict__ offs,
                        const unsigned* __restrict__ adjc, const int* __restrict__ perm,
                        float* __restrict__ outp) {
    int node = blockIdx.x * blockDim.x + threadIdx.x;
    if (node >= NTOT) return;
    float4 rt = RT[node];
    float a0 = rt.x, a1 = rt.y, a2 = rt.z;
    int e0 = offs[node], e1 = offs[node + 1];
    int e = e0;
    for (; e + 4 <= e1; e += 4) {
        unsigned q0 = __builtin_nontemporal_load(adjc + e);
        unsigned q1 = __builtin_nontemporal_load(adjc + e + 1);
        unsigned q2 = __builtin_nontemporal_load(adjc + e + 2);
        unsigned q3 = __builtin_nontemporal_load(adjc + e + 3);
        float4 h0 = H[q0 & SRCMASK], h1 = H[q1 & SRCMASK];
        float4 h2 = H[q2 & SRCMASK], h3 = H[q3 & SRCMASK];
        float n0 = dec_nm(q0), n1 = dec_nm(q1), n2 = dec_nm(q2), n3 = dec_nm(q3);
        a0 += n0 * h0.x; a1 += n0 * h0.y; a2 += n0 * h0.z;
        a0 += n1 * h1.x; a1 += n1 * h1.y; a2 += n1 * h1.z;
        a0 += n2 * h2.x; a1 += n2 * h2.y; a2 += n2 * h2.z;
        a0 += n3 * h3.x; a1 += n3 * h3.y; a2 += n3 * h3.z;
    }
    for (; e < e1; ++e) {
        unsigned q0 = __builtin_nontemporal_load(adjc + e);
        float4 h = H[q0 & SRCMASK];
        float nm = dec_nm(q0);
        a0 += nm * h.x; a1 += nm * h.y; a2 += nm * h.z;
    }
    a0 = fmaxf(a0, 0.f); a1 = fmaxf(a1, 0.f); a2 = fmaxf(a2, 0.f);
    if constexpr (LAST) {
        outp[perm[node]] = (a0 + a1 + a2) * (1.f / 3.f);
    } else {
        ((float4*)outp)[node] = make_float4(a0 * W_t[0], a1 * W_t[1], a2 * W_t[2], 0.f);
    }
}

// ---------------- batchnorm (+relu) ----------------

__global__ void k_bnstats(const float* __restrict__ x, float* __restrict__ stats, int F) {
    __shared__ float s1[256];
    __shared__ float s2[256];
    int tid = threadIdx.x;
    int gid = blockIdx.x * blockDim.x + tid;
    int stride = gridDim.x * blockDim.x;
    int total = NTOT * F;
    float a = 0.f, b = 0.f;
    for (int i = gid; i < total; i += stride) {
        float v = x[i];
        a += v;
        b += v * v;
    }
    s1[tid] = a; s2[tid] = b;
    __syncthreads();
    for (int s = 128; s >= F; s >>= 1) {
        if (tid < s) { s1[tid] += s1[tid + s]; s2[tid] += s2[tid + s]; }
        __syncthreads();
    }
    if (tid < F) {
        atomicAdd(&stats[tid], s1[tid]);
        atomicAdd(&stats[F + tid], s2[tid]);
    }
}

__global__ void k_bnapply32(float* __restrict__ x, const float* __restrict__ stats,
                            const float* __restrict__ g, const float* __restrict__ be,
                            unsigned* __restrict__ xbf) {
    int tid = blockIdx.x * blockDim.x + threadIdx.x;   // NTOT*16
    int f2 = tid & 15;
    int node = tid >> 4;
    int f0 = 2 * f2, f1 = f0 + 1;
    float mm0 = stats[f0] * (1.f / NTOT);
    float vv0 = stats[HID + f0] * (1.f / NTOT) - mm0 * mm0;
    float mm1 = stats[f1] * (1.f / NTOT);
    float vv1 = stats[HID + f1] * (1.f / NTOT) - mm1 * mm1;
    float y0 = fmaxf((x[(size_t)node * 32 + f0] - mm0) * rsqrtf(vv0 + EPSV) * g[f0] + be[f0], 0.f);
    float y1 = fmaxf((x[(size_t)node * 32 + f1] - mm1) * rsqrtf(vv1 + EPSV) * g[f1] + be[f1], 0.f);
    x[(size_t)node * 32 + f0] = y0;
    x[(size_t)node * 32 + f1] = y1;
    if (xbf) xbf[(size_t)(f2 >> 3) * NT8 + (size_t)node * 8 + (f2 & 7)] = pk(y0, y1);
}

__global__ void k_bnapply1(float* __restrict__ x, const float* __restrict__ stats,
                           const float* __restrict__ g, const float* __restrict__ be) {
    int i = blockIdx.x * blockDim.x + threadIdx.x;
    if (i >= NTOT) return;
    float m = stats[0] * (1.f / NTOT);
    float v = stats[1] * (1.f / NTOT) - m * m;
    float y = (x[i] - m) * rsqrtf(v + EPSV) * g[0] + be[0];
    x[i] = fmaxf(y, 0.f);
}

// ---------------- classifier + per-graph max ----------------

__global__ void k_final(const float* __restrict__ h, const float* __restrict__ cw,
                        const float* __restrict__ cb, float* __restrict__ out) {
    __shared__ float smax[256];
    int g = blockIdx.x;
    float cwv = cw[0], cbv = cb[0];
    float mx = -INFINITY;
    for (int i = threadIdx.x; i < NUM_NODES; i += blockDim.x) {
        int nidx = g * NUM_NODES + i;
        float v = h[nidx] * cwv + cbv;
        out[nidx] = v;
        mx = fmaxf(mx, v);
    }
    smax[threadIdx.x] = mx;
    __syncthreads();
    for (int s = 128; s >= 1; s >>= 1) {
        if (threadIdx.x < s) smax[threadIdx.x] = fmaxf(smax[threadIdx.x], smax[threadIdx.x + s]);
        __syncthreads();
    }
    if (threadIdx.x == 0) out[NTOT + g] = smax[0];
}

// ---------------- host launch ----------------

extern "C" void kernel_launch(void* const* d_in, const int* in_sizes, int n_in,
                              void* d_out, int out_size, void* d_ws, size_t ws_size,
                              hipStream_t stream) {
    const float* x   = (const float*)d_in[0];
    const int*   ei  = (const int*)d_in[1];
    const int*   row = ei;
    const int*   col = ei + NE;
    const float* wts = (const float*)d_in[2];
    const float* iw1 = (const float*)d_in[4];
    const float* w1  = (const float*)d_in[5];
    const float* rw1 = (const float*)d_in[6];
    const float* b1  = (const float*)d_in[7];
    const float* g1  = (const float*)d_in[8];
    const float* be1 = (const float*)d_in[9];
    const float* iw2 = (const float*)d_in[10];
    const float* w2  = (const float*)d_in[11];
    const float* rw2 = (const float*)d_in[12];
    const float* b2  = (const float*)d_in[13];
    const float* g2  = (const float*)d_in[14];
    const float* be2 = (const float*)d_in[15];
    const float* iw3 = (const float*)d_in[16];
    const float* w3  = (const float*)d_in[17];
    const float* rw3 = (const float*)d_in[18];
    const float* b3  = (const float*)d_in[19];
    const float* g3  = (const float*)d_in[20];
    const float* be3 = (const float*)d_in[21];
    const float* cw  = (const float*)d_in[22];
    const float* cb  = (const float*)d_in[23];
    float* out = (float*)d_out;

    char* p = (char*)d_ws;
    auto alloc = [&](size_t bytes) {
        char* r = p;
        p += (bytes + 255) & ~(size_t)255;
        return r;
    };
    // contiguous zero range: indegS, cnt, stats
    int*      indegS = (int*)alloc((size_t)NTOT * 16);
    int*      cnt    = (int*)alloc((size_t)CNTN * 4);
    float*    stats  = (float*)alloc(3 * 2 * HID * 4);
    char*     zend   = p;
    int*      indeg  = (int*)alloc((size_t)NTOT * 4);
    int*      bsum   = (int*)alloc((size_t)NBLK * 4);
    int*      offs   = (int*)alloc((size_t)(NTOT + 1) * 4);
    int*      cursor = (int*)alloc((size_t)NTOT * 4);
    int*      perm   = (int*)alloc((size_t)NTOT * 4);
    int*      invperm= (int*)alloc((size_t)NTOT * 4);
    int*      indegp = (int*)alloc((size_t)NTOT * 4);
    float*    disp   = (float*)alloc((size_t)NTOT * 4);
    unsigned* adjc   = (unsigned*)alloc((size_t)NE * 4);
    unsigned* OUTA   = (unsigned*)alloc((size_t)6 * NT8 * 4);   // 17.5MB (exact 256-mult)
    unsigned* OUTB   = (unsigned*)alloc((size_t)6 * NT8 * 4);   // contiguous after OUTA
    unsigned* P      = (unsigned*)alloc((size_t)6 * NT8 * 4);
    unsigned* xplane = (unsigned*)alloc((size_t)2 * NT8 * 4);   // 5.8MB
    float2*   xp     = (float2*)alloc((size_t)NTOT * 8);
    float2*   pag    = (float2*)alloc((size_t)NTOT * 8);
    float*    xa     = (float*)alloc((size_t)NTOT * HID * 4);
    float*    xb     = (float*)alloc((size_t)NTOT * HID * 4);
    float*    xc     = (float*)alloc((size_t)NTOT * 4);
    float4*   RT     = (float4*)alloc((size_t)TL * NTOT * 16);  // 7.3MB
    if ((size_t)(p - (char*)d_ws) > ws_size) return;

    // fp32 per-k LAST planes alias OUTA+OUTB (3*NTOT*32*4 = 2*17.5MB, exact);
    // safe: the plane Hc feeding the final gather is consumed before LAST writes.
    float* xo = (float*)OUTA;

    const int tb = 256;
    const int ebl = (NE + tb - 1) / tb;
    const int nbl = NTOT / tb;           // 356
    const int g16 = NTOT * 16 / tb;      // 5696

    hipMemsetAsync(indegS, 0, (size_t)(zend - (char*)indegS), stream);

    k_cnt<<<ebl, tb, 0, stream>>>(col, indegS);
    k_merge<<<nbl, tb, 0, stream>>>(indegS, indeg);
    k_lhist<<<NBLK, SCAN_B, 0, stream>>>(indeg, cnt);
    k_scan1<<<CNTB, SCAN_B, 0, stream>>>(cnt, bsum);
    k_scan2<<<1, 512, 0, stream>>>(bsum, CNTB);
    k_scan3<<<CNTB, SCAN_B, 0, stream>>>(cnt, bsum, cnt, -1, 0);
    k_rank<<<NBLK, SCAN_B, 0, stream>>>(indeg, cnt, perm, invperm, indegp);
    k_xp<<<nbl, tb, 0, stream>>>((const float2*)x, perm, xp);
    k_scan1<<<NBLK, SCAN_B, 0, stream>>>(indegp, bsum);
    k_scan2<<<1, 512, 0, stream>>>(bsum, NBLK);
    k_scan3<<<NBLK, SCAN_B, 0, stream>>>(indegp, bsum, offs, NTOT, NE);
    hipMemcpyAsync(cursor, offs, (size_t)NTOT * 4, hipMemcpyDeviceToDevice, stream);
    k_fill<<<ebl, tb, 0, stream>>>(row, col, wts, invperm, cursor, adjc);
    k_degdis<<<nbl, tb, 0, stream>>>(adjc, offs, disp);
    k_norm<<<nbl, tb, 0, stream>>>(adjc, offs, disp);

    // ---- layer 1: 2 -> 32 ----
    {
        k_gath2<<<nbl, tb, 0, stream>>>(xp, offs, adjc, pag);
        k_x0<<<g16, tb, 0, stream>>>(pag, xp, iw1, rw1, b1, OUTA);
        unsigned* Hc = OUTA; unsigned* Hn = OUTB;
        for (int t = 1; t < TL - 1; ++t) {
            k_gath<<<6 * NB128, tb, 0, stream>>>(Hc, offs, adjc, P);
            k_xformk<2, false, false><<<3 * NB128, tb, 0, stream>>>(
                P, (const float*)xp, w1 + (size_t)(t - 1) * KS * HID * HID,
                rw1 + (size_t)t * KS * 2 * HID, b1 + (size_t)t * KS * HID, Hn);
            unsigned* tmp = Hc; Hc = Hn; Hn = tmp;
        }
        k_gath<<<6 * NB128, tb, 0, stream>>>(Hc, offs, adjc, P);
        k_xformk<2, false, true><<<3 * NB128, tb, 0, stream>>>(
            P, (const float*)xp, w1 + (size_t)(TL - 2) * KS * HID * HID,
            rw1 + (size_t)(TL - 1) * KS * 2 * HID, b1 + (size_t)(TL - 1) * KS * HID, xo);
        k_meanstats<<<256, tb, 0, stream>>>(xo, xo + (size_t)NTOT * HID,
                                            xo + (size_t)2 * NTOT * HID, xa, stats);
        k_bnapply32<<<g16, tb, 0, stream>>>(xa, stats, g1, be1, xplane);
    }
    // ---- layer 2: 32 -> 32 ----
    {
        k_gath<<<2 * NB128, tb, 0, stream>>>(xplane, offs, adjc, P);
        k_xformk<32, true, false><<<3 * NB128, tb, 0, stream>>>(
            P, xa, iw2, rw2, b2, OUTA);
        unsigned* Hc = OUTA; unsigned* Hn = OUTB;
        for (int t = 1; t < TL - 1; ++t) {
            k_gath<<<6 * NB128, tb, 0, stream>>>(Hc, offs, adjc, P);
            k_xformk<32, false, false><<<3 * NB128, tb, 0, stream>>>(
                P, xa, w2 + (size_t)(t - 1) * KS * HID * HID,
                rw2 + (size_t)t * KS * HID * HID, b2 + (size_t)t * KS * HID, Hn);
            unsigned* tmp = Hc; Hc = Hn; Hn = tmp;
        }
        k_gath<<<6 * NB128, tb, 0, stream>>>(Hc, offs, adjc, P);
        k_xformk<32, false, true><<<3 * NB128, tb, 0, stream>>>(
            P, xa, w2 + (size_t)(TL - 2) * KS * HID * HID,
            rw2 + (size_t)(TL - 1) * KS * HID * HID, b2 + (size_t)(TL - 1) * KS * HID, xo);
        k_meanstats<<<256, tb, 0, stream>>>(xo, xo + (size_t)NTOT * HID,
                                            xo + (size_t)2 * NTOT * HID, xb, stats + 2 * HID);
        k_bnapply32<<<g16, tb, 0, stream>>>(xb, stats + 2 * HID, g2, be2, nullptr);
    }
    // ---- layer 3: 32 -> 1 ----
    {
        float4* HAf = (float4*)OUTA;
        float4* HBf = (float4*)OUTB;
        k_rec3<<<nbl, tb, 0, stream>>>(xb, iw3, rw3, b3, HAf, RT);
        const float4* Hc = HAf; float4* Hn = HBf;
        for (int t = 0; t < TL - 1; ++t) {
            k_prop1<false><<<nbl, tb, 0, stream>>>(
                Hc, RT + (size_t)t * NTOT, w3 + (size_t)t * KS, offs, adjc, perm, (float*)Hn);
            const float4* tmp = Hc; Hc = Hn; Hn = (float4*)tmp;
        }
        k_prop1<true><<<nbl, tb, 0, stream>>>(
            Hc, RT + (size_t)(TL - 1) * NTOT, nullptr, offs, adjc, perm, xc);
        k_bnstats<<<256, tb, 0, stream>>>(xc, stats + 4 * HID, 1);
        k_bnapply1<<<nbl, tb, 0, stream>>>(xc, stats + 4 * HID, g3, be3);
    }

    k_final<<<N_GRAPHS, 256, 0, stream>>>(xc, cw, cb, out);
}